// Round 7
// baseline (66.973 us; speedup 1.0000x reference)
//
#include <hip/hip_runtime.h>

#define T_FRAMES 75
#define C_CH 3
#define HW4 (112 * 112 / 4)    // 3136 float4 per frame-slab
#define P_DEL 0.05f
#define COPY_THREADS 448       // 7 waves; 2 slabs: 2*3136 / 448 == 14 exactly

typedef float f32x4 __attribute__((ext_vector_type(4)));

// Replay the reference scan for ONE output slot j given the 75-bit delete
// mask. Returns the INPUT frame index slot j ends up holding.
__device__ __forceinline__ int jitter_replay(unsigned long long m0,
                                             unsigned long long m1, int j) {
    int s = j;      // out starts as a copy of input
    int cnt = 0;
    for (int t = 0; t < T_FRAMES; ++t) {
        int d  = (int)(((t < 64 ? m0 : m1) >> (t & 63)) & 1ull);
        int rt = T_FRAMES - 1 - t;              // prob_dup[t] = prob_del[T-1-t]
        int dp = (int)(((rt < 64 ? m0 : m1) >> (rt & 63)) & 1ull);
        if (!d && cnt < T_FRAMES) {             // keep frame t
            if (cnt == j) s = t;
            ++cnt;
        }
        if (dp && cnt > 0 && cnt < T_FRAMES) {  // dup from INPUT index cnt-1
            if (cnt == j) s = cnt - 1;
            ++cnt;
        }
        if (cnt > j) break;                     // cnt monotone
    }
    return s;
}

// Same replay tracking TWO slots in one pass (for a slab pair sharing the
// same batch mask).
__device__ __forceinline__ void jitter_replay2(unsigned long long m0,
                                               unsigned long long m1,
                                               int j0, int j1,
                                               int& s0, int& s1) {
    s0 = j0; s1 = j1;
    int jmax = (j1 > j0) ? j1 : j0;
    int cnt = 0;
    for (int t = 0; t < T_FRAMES; ++t) {
        int d  = (int)(((t < 64 ? m0 : m1) >> (t & 63)) & 1ull);
        int rt = T_FRAMES - 1 - t;
        int dp = (int)(((rt < 64 ? m0 : m1) >> (rt & 63)) & 1ull);
        if (!d && cnt < T_FRAMES) {
            if (cnt == j0) s0 = t;
            if (cnt == j1) s1 = t;
            ++cnt;
        }
        if (dp && cnt > 0 && cnt < T_FRAMES) {
            if (cnt == j0) s0 = cnt - 1;
            if (cnt == j1) s1 = cnt - 1;
            ++cnt;
        }
        if (cnt > jmax) break;
    }
}

// Build the 75-bit delete mask for batch b via two wave ballots.
__device__ __forceinline__ void build_mask(const float* __restrict__ u, int b,
                                           int lane, unsigned long long& m0,
                                           unsigned long long& m1) {
    const float* ub = u + b * T_FRAMES;
    float v0 = ub[lane];                                  // lanes 0..63
    m0 = __ballot(v0 < P_DEL);
    float v1 = (lane < T_FRAMES - 64) ? ub[64 + lane] : 1.0f;
    m1 = __ballot(v1 < P_DEL);
}

// One block per pair of (b, c, j) output frame-slabs. Every wave redundantly
// computes the two source indices (no LDS, no barrier: u loads are L1-hits,
// replay is wave-uniform and hides under other waves' memory stalls), then
// does a 14-deep float4 copy with nontemporal stores.
__global__ void __launch_bounds__(COPY_THREADS)
jitter_fused_kernel(const f32x4* __restrict__ x,
                    f32x4* __restrict__ out,
                    const float* __restrict__ u) {
    int slab0 = blockIdx.x * 2;                   // [0, B*C*T) in pairs
    int slab1 = slab0 + 1;
    int bc0 = slab0 / T_FRAMES, j0 = slab0 % T_FRAMES;
    int bc1 = slab1 / T_FRAMES, j1 = slab1 % T_FRAMES;
    int b0  = bc0 / C_CH,       b1  = bc1 / C_CH;

    int lane = threadIdx.x & 63;
    unsigned long long m0, m1;
    build_mask(u, b0, lane, m0, m1);

    int s0, s1;
    if (b1 == b0) {
        jitter_replay2(m0, m1, j0, j1, s0, s1);
    } else {                                      // rare: pair crosses batch
        s0 = jitter_replay(m0, m1, j0);
        unsigned long long n0, n1;
        build_mask(u, b1, lane, n0, n1);
        s1 = jitter_replay(n0, n1, j1);
    }

    const f32x4* sp0 = x   + ((size_t)bc0 * T_FRAMES + s0) * HW4;
    const f32x4* sp1 = x   + ((size_t)bc1 * T_FRAMES + s1) * HW4;
    f32x4*       dp0 = out + (size_t)slab0 * HW4;
    f32x4*       dp1 = out + (size_t)slab1 * HW4;

    int i = threadIdx.x;
    f32x4 a0 = sp0[i + 0 * COPY_THREADS];
    f32x4 a1 = sp0[i + 1 * COPY_THREADS];
    f32x4 a2 = sp0[i + 2 * COPY_THREADS];
    f32x4 a3 = sp0[i + 3 * COPY_THREADS];
    f32x4 a4 = sp0[i + 4 * COPY_THREADS];
    f32x4 a5 = sp0[i + 5 * COPY_THREADS];
    f32x4 a6 = sp0[i + 6 * COPY_THREADS];
    f32x4 c0 = sp1[i + 0 * COPY_THREADS];
    f32x4 c1 = sp1[i + 1 * COPY_THREADS];
    f32x4 c2 = sp1[i + 2 * COPY_THREADS];
    f32x4 c3 = sp1[i + 3 * COPY_THREADS];
    f32x4 c4 = sp1[i + 4 * COPY_THREADS];
    f32x4 c5 = sp1[i + 5 * COPY_THREADS];
    f32x4 c6 = sp1[i + 6 * COPY_THREADS];
    __builtin_nontemporal_store(a0, &dp0[i + 0 * COPY_THREADS]);
    __builtin_nontemporal_store(a1, &dp0[i + 1 * COPY_THREADS]);
    __builtin_nontemporal_store(a2, &dp0[i + 2 * COPY_THREADS]);
    __builtin_nontemporal_store(a3, &dp0[i + 3 * COPY_THREADS]);
    __builtin_nontemporal_store(a4, &dp0[i + 4 * COPY_THREADS]);
    __builtin_nontemporal_store(a5, &dp0[i + 5 * COPY_THREADS]);
    __builtin_nontemporal_store(a6, &dp0[i + 6 * COPY_THREADS]);
    __builtin_nontemporal_store(c0, &dp1[i + 0 * COPY_THREADS]);
    __builtin_nontemporal_store(c1, &dp1[i + 1 * COPY_THREADS]);
    __builtin_nontemporal_store(c2, &dp1[i + 2 * COPY_THREADS]);
    __builtin_nontemporal_store(c3, &dp1[i + 3 * COPY_THREADS]);
    __builtin_nontemporal_store(c4, &dp1[i + 4 * COPY_THREADS]);
    __builtin_nontemporal_store(c5, &dp1[i + 5 * COPY_THREADS]);
    __builtin_nontemporal_store(c6, &dp1[i + 6 * COPY_THREADS]);
}

extern "C" void kernel_launch(void* const* d_in, const int* in_sizes, int n_in,
                              void* d_out, int out_size, void* d_ws, size_t ws_size,
                              hipStream_t stream) {
    const float* x = (const float*)d_in[0];       // [B, C, T, H, W] fp32
    const float* u = (const float*)d_in[1];       // [B, T] fp32
    float* out = (float*)d_out;

    int B = in_sizes[1] / T_FRAMES;               // 16
    int slab_pairs = B * C_CH * T_FRAMES / 2;     // 1800

    jitter_fused_kernel<<<slab_pairs, COPY_THREADS, 0, stream>>>(
        (const f32x4*)x, (f32x4*)out, u);
}

// Round 8
// 62.056 us; speedup vs baseline: 1.0792x; 1.0792x over previous
//
#include <hip/hip_runtime.h>

#define T_FRAMES 75
#define C_CH 3
#define HW4 (112 * 112 / 4)    // 3136 float4 per frame-slab
#define P_DEL 0.05f
#define COPY_THREADS 448       // 7 waves; 2 slabs: 2*3136 / 448 == 14 exactly

typedef float f32x4 __attribute__((ext_vector_type(4)));

// Replay the reference scan for ONE output slot j given the 75-bit delete
// mask (m0 = bits 0..63, m1 = bits 64..74). Returns the INPUT frame index
// that slot j ends up holding. cnt is monotone -> early break once cnt > j.
__device__ __forceinline__ int jitter_replay(unsigned long long m0,
                                             unsigned long long m1, int j) {
    int s = j;      // out starts as a copy of input
    int cnt = 0;
    for (int t = 0; t < T_FRAMES; ++t) {
        int d  = (int)(((t < 64 ? m0 : m1) >> (t & 63)) & 1ull);
        int rt = T_FRAMES - 1 - t;              // prob_dup[t] = prob_del[T-1-t]
        int dp = (int)(((rt < 64 ? m0 : m1) >> (rt & 63)) & 1ull);
        if (!d && cnt < T_FRAMES) {             // keep frame t
            if (cnt == j) s = t;
            ++cnt;
        }
        if (dp && cnt > 0 && cnt < T_FRAMES) {  // dup from INPUT index cnt-1
            if (cnt == j) s = cnt - 1;
            ++cnt;
        }
        if (cnt > j) break;                     // uniform across lanes
    }
    return s;
}

// Build the 75-bit delete mask for batch b via two wave ballots.
__device__ __forceinline__ void build_mask(const float* __restrict__ u, int b,
                                           int lane, unsigned long long& m0,
                                           unsigned long long& m1) {
    const float* ub = u + b * T_FRAMES;
    float v0 = ub[lane];                                  // lanes 0..63
    m0 = __ballot(v0 < P_DEL);
    float v1 = (lane < T_FRAMES - 64) ? ub[64 + lane] : 1.0f;
    m1 = __ballot(v1 < P_DEL);
}

// One block per pair of (b, c, j) output frame-slabs. Wave 0 computes the
// two source indices (ballot masks + early-break replay), broadcasts via
// LDS; all 7 waves then do a 14-deep float4 copy with nontemporal stores.
// (Round 7 showed redundant per-wave replay regresses: single-wave uniform
// work + barrier broadcast is the right structure.)
__global__ void __launch_bounds__(COPY_THREADS)
jitter_fused_kernel(const f32x4* __restrict__ x,
                    f32x4* __restrict__ out,
                    const float* __restrict__ u) {
    __shared__ int s_lds[2];

    int slab0 = blockIdx.x * 2;                   // [0, B*C*T) in pairs
    int slab1 = slab0 + 1;
    int bc0 = slab0 / T_FRAMES, j0 = slab0 % T_FRAMES;
    int bc1 = slab1 / T_FRAMES, j1 = slab1 % T_FRAMES;
    int b0  = bc0 / C_CH,       b1  = bc1 / C_CH;

    if (threadIdx.x < 64) {                       // wave 0 only
        int lane = threadIdx.x;
        unsigned long long m0, m1;
        build_mask(u, b0, lane, m0, m1);
        int s0 = jitter_replay(m0, m1, j0);
        int s1;
        if (b1 == b0) {
            s1 = jitter_replay(m0, m1, j1);
        } else {
            unsigned long long n0, n1;
            build_mask(u, b1, lane, n0, n1);
            s1 = jitter_replay(n0, n1, j1);
        }
        if (lane == 0) { s_lds[0] = s0; s_lds[1] = s1; }
    }
    __syncthreads();
    int s0 = s_lds[0];
    int s1 = s_lds[1];

    const f32x4* sp0 = x   + ((size_t)bc0 * T_FRAMES + s0) * HW4;
    const f32x4* sp1 = x   + ((size_t)bc1 * T_FRAMES + s1) * HW4;
    f32x4*       dp0 = out + (size_t)slab0 * HW4;
    f32x4*       dp1 = out + (size_t)slab1 * HW4;

    int i = threadIdx.x;
    f32x4 a0 = sp0[i + 0 * COPY_THREADS];
    f32x4 a1 = sp0[i + 1 * COPY_THREADS];
    f32x4 a2 = sp0[i + 2 * COPY_THREADS];
    f32x4 a3 = sp0[i + 3 * COPY_THREADS];
    f32x4 a4 = sp0[i + 4 * COPY_THREADS];
    f32x4 a5 = sp0[i + 5 * COPY_THREADS];
    f32x4 a6 = sp0[i + 6 * COPY_THREADS];
    f32x4 c0 = sp1[i + 0 * COPY_THREADS];
    f32x4 c1 = sp1[i + 1 * COPY_THREADS];
    f32x4 c2 = sp1[i + 2 * COPY_THREADS];
    f32x4 c3 = sp1[i + 3 * COPY_THREADS];
    f32x4 c4 = sp1[i + 4 * COPY_THREADS];
    f32x4 c5 = sp1[i + 5 * COPY_THREADS];
    f32x4 c6 = sp1[i + 6 * COPY_THREADS];
    __builtin_nontemporal_store(a0, &dp0[i + 0 * COPY_THREADS]);
    __builtin_nontemporal_store(a1, &dp0[i + 1 * COPY_THREADS]);
    __builtin_nontemporal_store(a2, &dp0[i + 2 * COPY_THREADS]);
    __builtin_nontemporal_store(a3, &dp0[i + 3 * COPY_THREADS]);
    __builtin_nontemporal_store(a4, &dp0[i + 4 * COPY_THREADS]);
    __builtin_nontemporal_store(a5, &dp0[i + 5 * COPY_THREADS]);
    __builtin_nontemporal_store(a6, &dp0[i + 6 * COPY_THREADS]);
    __builtin_nontemporal_store(c0, &dp1[i + 0 * COPY_THREADS]);
    __builtin_nontemporal_store(c1, &dp1[i + 1 * COPY_THREADS]);
    __builtin_nontemporal_store(c2, &dp1[i + 2 * COPY_THREADS]);
    __builtin_nontemporal_store(c3, &dp1[i + 3 * COPY_THREADS]);
    __builtin_nontemporal_store(c4, &dp1[i + 4 * COPY_THREADS]);
    __builtin_nontemporal_store(c5, &dp1[i + 5 * COPY_THREADS]);
    __builtin_nontemporal_store(c6, &dp1[i + 6 * COPY_THREADS]);
}

extern "C" void kernel_launch(void* const* d_in, const int* in_sizes, int n_in,
                              void* d_out, int out_size, void* d_ws, size_t ws_size,
                              hipStream_t stream) {
    const float* x = (const float*)d_in[0];       // [B, C, T, H, W] fp32
    const float* u = (const float*)d_in[1];       // [B, T] fp32
    float* out = (float*)d_out;

    int B = in_sizes[1] / T_FRAMES;               // 16
    int slab_pairs = B * C_CH * T_FRAMES / 2;     // 1800

    jitter_fused_kernel<<<slab_pairs, COPY_THREADS, 0, stream>>>(
        (const f32x4*)x, (f32x4*)out, u);
}